// Round 5
// baseline (420.423 us; speedup 1.0000x reference)
//
#include <hip/hip_runtime.h>
#include <hip/hip_bf16.h>
#include <cstdint>

typedef __hip_bfloat16 bf16;
typedef __attribute__((ext_vector_type(8))) short bf16x8;
typedef __attribute__((ext_vector_type(4))) float f32x4;

#define T_SEQ 2048
#define DMODEL 1024
#define NHEAD 16
#define DHEAD 64
#define MROWS 4096

typedef const __attribute__((address_space(1))) void* gas_ptr;
typedef __attribute__((address_space(3))) void* las_ptr;

static __device__ __forceinline__ f32x4 mfma16(bf16x8 a, bf16x8 b, f32x4 c) {
  return __builtin_amdgcn_mfma_f32_16x16x32_bf16(a, b, c, 0, 0, 0);
}
static __device__ __forceinline__ void gload_lds16(const void* g, void* l) {
  __builtin_amdgcn_global_load_lds((gas_ptr)g, (las_ptr)l, 16, 0, 0);
}
static __device__ __forceinline__ float b2f(unsigned short u) {
  union { unsigned int i; float f; } x; x.i = ((unsigned int)u) << 16; return x.f;
}
static __device__ __forceinline__ unsigned short f2bu(float f) {
  __hip_bfloat16 h = __float2bfloat16(f);
  unsigned short u; __builtin_memcpy(&u, &h, 2); return u;
}

// ---------------- weight fp32 -> bf16 ----------------
__global__ void f2b_k(const float* __restrict__ in, bf16* __restrict__ out, int n) {
  int idx = (blockIdx.x * blockDim.x + threadIdx.x) * 4;
  if (idx < n) {
    float4 v = *(const float4*)(in + idx);
    out[idx]     = __float2bfloat16(v.x);
    out[idx + 1] = __float2bfloat16(v.y);
    out[idx + 2] = __float2bfloat16(v.z);
    out[idx + 3] = __float2bfloat16(v.w);
  }
}

// ---------------- RMSNorm: fp32 in -> bf16 out ----------------
__global__ __launch_bounds__(256) void rms_k(const float* __restrict__ x,
                                             const float* __restrict__ w,
                                             bf16* __restrict__ out) {
  const int row = blockIdx.x;
  const int tid = threadIdx.x;
  const float4 v = ((const float4*)(x + (size_t)row * DMODEL))[tid];
  float ss = v.x * v.x + v.y * v.y + v.z * v.z + v.w * v.w;
#pragma unroll
  for (int off = 32; off; off >>= 1) ss += __shfl_xor(ss, off);
  __shared__ float red[4];
  if ((tid & 63) == 0) red[tid >> 6] = ss;
  __syncthreads();
  const float tot = red[0] + red[1] + red[2] + red[3];
  const float rinv = rsqrtf(tot * (1.f / DMODEL) + 1e-6f);
  const float4 wv = ((const float4*)w)[tid];
  bf16* o = out + (size_t)row * DMODEL + tid * 4;
  o[0] = __float2bfloat16(v.x * rinv * wv.x);
  o[1] = __float2bfloat16(v.y * rinv * wv.y);
  o[2] = __float2bfloat16(v.z * rinv * wv.z);
  o[3] = __float2bfloat16(v.w * rinv * wv.w);
}

// ---------------- GEMM: C = A(M,K) x Bw(N,K)^T, bf16 in, fp32 accum ----------------
// m97 structure: 128x128 tile, BK=32, 4 waves, global_load_lds width=16.
// EPI: 0 = bf16 store to o0 (ld=N)
//      1 = qkv scatter: Q,K as (B,H,T,64) to o0/o1; V TRANSPOSED as (B,H,64,T) to o2
//      2 = fp32 store o0 = res + C (ld=N)
//      3 = split-N: cols [0,N/2) -> o0, [N/2,N) -> o1, each compact ld=N/2 bf16
template <int K, int EPI>
__global__ __launch_bounds__(256) void gemm_bt(const bf16* __restrict__ A,
                                               const bf16* __restrict__ Bw, int N,
                                               void* __restrict__ o0, void* __restrict__ o1,
                                               void* __restrict__ o2,
                                               const float* __restrict__ res) {
  __shared__ bf16 As[128 * 32];
  __shared__ bf16 Bs[128 * 32];
  const int bn0 = blockIdx.x * 128;
  const int bm0 = blockIdx.y * 128;
  const int tid = threadIdx.x;
  const int wave = tid >> 6, lane = tid & 63;
  const int wr = wave >> 1, wc = wave & 1;
  const int fr = lane & 15, g8 = (lane >> 4) * 8, r4 = (lane >> 4) * 4;
  const int srow = lane >> 2;
  const int scol = (lane & 3) * 8;

  const f32x4 fzero = {0.f, 0.f, 0.f, 0.f};
  f32x4 acc[4][4];
#pragma unroll
  for (int i = 0; i < 4; i++)
#pragma unroll
    for (int j = 0; j < 4; j++) acc[i][j] = fzero;

  const bf16* gA0 = A + (size_t)(bm0 + wave * 16 + srow) * K + scol;
  const bf16* gA1 = A + (size_t)(bm0 + (wave + 4) * 16 + srow) * K + scol;
  const bf16* gB0 = Bw + (size_t)(bn0 + wave * 16 + srow) * K + scol;
  const bf16* gB1 = Bw + (size_t)(bn0 + (wave + 4) * 16 + srow) * K + scol;

  for (int k0 = 0; k0 < K; k0 += 32) {
    gload_lds16(gA0 + k0, &As[wave * 512]);
    gload_lds16(gA1 + k0, &As[(wave + 4) * 512]);
    gload_lds16(gB0 + k0, &Bs[wave * 512]);
    gload_lds16(gB1 + k0, &Bs[(wave + 4) * 512]);
    __syncthreads();
    bf16x8 af[4], bfr[4];
#pragma unroll
    for (int mr = 0; mr < 4; mr++)
      af[mr] = *(const bf16x8*)&As[(wr * 64 + mr * 16 + fr) * 32 + g8];
#pragma unroll
    for (int nr = 0; nr < 4; nr++)
      bfr[nr] = *(const bf16x8*)&Bs[(wc * 64 + nr * 16 + fr) * 32 + g8];
#pragma unroll
    for (int mr = 0; mr < 4; mr++)
#pragma unroll
      for (int nr = 0; nr < 4; nr++)
        acc[mr][nr] = mfma16(af[mr], bfr[nr], acc[mr][nr]);
    __syncthreads();
  }

#pragma unroll
  for (int mr = 0; mr < 4; mr++) {
#pragma unroll
    for (int nr = 0; nr < 4; nr++) {
#pragma unroll
      for (int r = 0; r < 4; r++) {
        const int row = bm0 + wr * 64 + mr * 16 + r4 + r;
        const int col = bn0 + wc * 64 + nr * 16 + fr;
        const float vsum = acc[mr][nr][r];
        if (EPI == 0) {
          ((bf16*)o0)[(size_t)row * N + col] = __float2bfloat16(vsum);
        } else if (EPI == 1) {
          const int sel = col >> 10;
          const int n = col & 1023;
          const int h = n >> 6, d = n & 63;
          const int b = row >> 11, t = row & 2047;
          if (sel == 2) {
            // V transposed: (B,H,D,T)
            ((bf16*)o2)[(((size_t)(b * NHEAD + h)) * DHEAD + d) * T_SEQ + t] =
                __float2bfloat16(vsum);
          } else {
            bf16* dst = (sel == 0) ? (bf16*)o0 : (bf16*)o1;
            dst[(((size_t)(b * NHEAD + h)) * T_SEQ + t) * DHEAD + d] = __float2bfloat16(vsum);
          }
        } else if (EPI == 2) {
          ((float*)o0)[(size_t)row * N + col] = res[(size_t)row * N + col] + vsum;
        } else {
          const int half = N >> 1;
          bf16* dst = (col < half) ? (bf16*)o0 : (bf16*)o1;
          const int c = (col < half) ? col : col - half;
          dst[(size_t)row * half + c] = __float2bfloat16(vsum);
        }
      }
    }
  }
}

// ---------------- causal flash attention ----------------
// 4096 independent wave-tasks: one 16-row Q-group per wave (max parallelism).
// Block mapping is XCD- and balance-aware:
//   xcd c = blockIdx.x & 7 (blocks round-robin over XCDs), i = blockIdx.x >> 3;
//   bh = c*4 + (i>>5)  -> each XCD serves 4 heads; its L2 holds their K/V (2MB).
//   g  = 127 - ((i&31)*4 + wave) -> heavy (long key-range) tasks dispatch first,
//   and the 4 waves of a block have near-equal length.
// Unnormalized softmax: p = exp(min(s*0.125,30)) — shift-invariant, exact.
// P handoff: per-wave double-buffered LDS slice; wave-local fence
// (s_waitcnt lgkmcnt(0) + memory clobber + sched_barrier) orders write->read.
__global__ __launch_bounds__(256) void attn_k(const bf16* __restrict__ qb,
                                              const bf16* __restrict__ kb,
                                              const bf16* __restrict__ vt,
                                              bf16* __restrict__ y) {
  const int wave = threadIdx.x >> 6, lane = threadIdx.x & 63;
  const int c = blockIdx.x & 7;
  const int i = blockIdx.x >> 3;
  const int bh = c * 4 + (i >> 5);
  const int g = 127 - ((i & 31) * 4 + wave);
  const int b = bh >> 4, h = bh & 15;
  const int fr = lane & 15, g8 = (lane >> 4) * 8, r4 = (lane >> 4) * 4;

  const bf16* qp = qb + (size_t)bh * T_SEQ * DHEAD;
  const bf16* kp = kb + (size_t)bh * T_SEQ * DHEAD;
  const bf16* vp = vt + (size_t)bh * DHEAD * T_SEQ;

  __shared__ short pl[4][2][16][32];
  short(*plw)[16][32] = pl[wave];

  const f32x4 fzero = {0.f, 0.f, 0.f, 0.f};

  const int q0 = g * 16;
  const int kend = q0 + 16;

  const bf16x8 qf0 = *(const bf16x8*)(qp + (size_t)(q0 + fr) * DHEAD + g8);
  const bf16x8 qf1 = *(const bf16x8*)(qp + (size_t)(q0 + fr) * DHEAD + 32 + g8);

  f32x4 acc[4];
  float lsum[4];
#pragma unroll
  for (int nf = 0; nf < 4; nf++) acc[nf] = fzero;
#pragma unroll
  for (int r = 0; r < 4; r++) lsum[r] = 0.f;

  for (int kt = 0; kt < kend; kt += 32) {
    const int buf = (kt >> 5) & 1;
    // K fragments (L2-resident by construction)
    const bf16x8 kf0a = *(const bf16x8*)(kp + (size_t)(kt + fr) * DHEAD + g8);
    const bf16x8 kf0b = *(const bf16x8*)(kp + (size_t)(kt + fr) * DHEAD + 32 + g8);
    const bf16x8 kf1a = *(const bf16x8*)(kp + (size_t)(kt + 16 + fr) * DHEAD + g8);
    const bf16x8 kf1b = *(const bf16x8*)(kp + (size_t)(kt + 16 + fr) * DHEAD + 32 + g8);

    f32x4 s0 = mfma16(qf0, kf0a, fzero);
    s0 = mfma16(qf1, kf0b, s0);
    f32x4 s1 = mfma16(qf0, kf1a, fzero);
    s1 = mfma16(qf1, kf1b, s1);

#pragma unroll
    for (int r = 0; r < 4; r++) {
      const int qrow = q0 + r4 + r;
      const float x0 =
          (kt + fr <= qrow) ? __expf(fminf(s0[r] * 0.125f, 30.f)) : 0.f;
      const float x1 =
          (kt + 16 + fr <= qrow) ? __expf(fminf(s1[r] * 0.125f, 30.f)) : 0.f;
      lsum[r] += x0 + x1;
      plw[buf][r4 + r][fr] = (short)f2bu(x0);
      plw[buf][r4 + r][16 + fr] = (short)f2bu(x1);
    }
    // wave-local handoff fence: order P-writes before P-read, wait completion
    asm volatile("s_waitcnt lgkmcnt(0)" ::: "memory");
    __builtin_amdgcn_sched_barrier(0);
    const bf16x8 pa = *(const bf16x8*)&plw[buf][fr][g8];
#pragma unroll
    for (int nf = 0; nf < 4; nf++) {
      const bf16x8 vf =
          *(const bf16x8*)(vp + (size_t)(nf * 16 + fr) * T_SEQ + kt + g8);
      acc[nf] = mfma16(pa, vf, acc[nf]);
    }
  }

  // reduce per-lane partial lsum across the 16 lanes (fr) sharing each row
#pragma unroll
  for (int r = 0; r < 4; r++) {
    float s = lsum[r];
    s += __shfl_xor(s, 1);
    s += __shfl_xor(s, 2);
    s += __shfl_xor(s, 4);
    s += __shfl_xor(s, 8);
    lsum[r] = 1.f / s;
  }

#pragma unroll
  for (int r = 0; r < 4; r++) {
    const int t = q0 + r4 + r;
#pragma unroll
    for (int nf = 0; nf < 4; nf++) {
      const int d = nf * 16 + fr;
      y[(((size_t)(b * T_SEQ + t)) * NHEAD + h) * DHEAD + d] =
          __float2bfloat16(acc[nf][r] * lsum[r]);
    }
  }
}

// ---------------- gu = silu(g) * u (bf16) ----------------
__global__ void silumul_k(const bf16* __restrict__ g, const bf16* __restrict__ u,
                          bf16* __restrict__ o, int n) {
  const int idx = (blockIdx.x * blockDim.x + threadIdx.x) * 4;
  if (idx < n) {
    const ushort4 gv = *(const ushort4*)((const unsigned short*)g + idx);
    const ushort4 uv = *(const ushort4*)((const unsigned short*)u + idx);
    ushort4 ov;
    float a, s;
    a = b2f(gv.x); s = a / (1.f + __expf(-a)); ov.x = f2bu(s * b2f(uv.x));
    a = b2f(gv.y); s = a / (1.f + __expf(-a)); ov.y = f2bu(s * b2f(uv.y));
    a = b2f(gv.z); s = a / (1.f + __expf(-a)); ov.z = f2bu(s * b2f(uv.z));
    a = b2f(gv.w); s = a / (1.f + __expf(-a)); ov.w = f2bu(s * b2f(uv.w));
    *(ushort4*)((unsigned short*)o + idx) = ov;
  }
}

// ---------------- launch ----------------
extern "C" void kernel_launch(void* const* d_in, const int* in_sizes, int n_in,
                              void* d_out, int out_size, void* d_ws, size_t ws_size,
                              hipStream_t stream) {
  const float* x     = (const float*)d_in[0];
  const float* ln1w  = (const float*)d_in[1];
  const float* ln2w  = (const float*)d_in[2];
  const float* qkvw  = (const float*)d_in[3];
  const float* ow    = (const float*)d_in[4];
  const float* gatew = (const float*)d_in[5];
  const float* upw   = (const float*)d_in[6];
  const float* downw = (const float*)d_in[7];

  uint8_t* ws = (uint8_t*)d_ws;
  // workspace layout (bytes); ~80 MB total with aliasing
  bf16* WQKV = (bf16*)(ws + 0);          // 6291456
  bf16* WO   = (bf16*)(ws + 6291456);    // 2097152
  bf16* WG   = (bf16*)(ws + 8388608);    // 4194304  (WU must follow contiguously)
  bf16* WU   = (bf16*)(ws + 12582912);   // 4194304
  bf16* WD   = (bf16*)(ws + 16777216);   // 4194304
  bf16* H    = (bf16*)(ws + 20971520);   // 8388608
  bf16* Q    = (bf16*)(ws + 29360128);   // 8388608
  bf16* Kb   = (bf16*)(ws + 37748736);   // 8388608
  bf16* VT   = (bf16*)(ws + 46137344);   // 8388608  (B,H,64,T)
  bf16* Y    = (bf16*)(ws + 54525952);   // 8388608
  float* X2  = (float*)(ws + 62914560);  // 16777216 -> end 79691776
  // FFN phase aliases (Q/Kb/VT/Y dead after o-proj):
  bf16* G = (bf16*)(ws + 29360128);      // 16777216 (4096 x 2048)
  bf16* U = (bf16*)(ws + 46137344);      // 16777216 (4096 x 2048)

  // weights -> bf16
  f2b_k<<<3072, 256, 0, stream>>>(qkvw, WQKV, 3072 * 1024);
  f2b_k<<<1024, 256, 0, stream>>>(ow, WO, 1024 * 1024);
  f2b_k<<<2048, 256, 0, stream>>>(gatew, WG, 2048 * 1024);
  f2b_k<<<2048, 256, 0, stream>>>(upw, WU, 2048 * 1024);
  f2b_k<<<2048, 256, 0, stream>>>(downw, WD, 1024 * 2048);

  // attn path
  rms_k<<<MROWS, 256, 0, stream>>>(x, ln1w, H);
  gemm_bt<1024, 1><<<dim3(24, 32), 256, 0, stream>>>(H, WQKV, 3072, Q, Kb, VT, nullptr);
  attn_k<<<1024, 256, 0, stream>>>(Q, Kb, VT, Y);
  gemm_bt<1024, 2><<<dim3(8, 32), 256, 0, stream>>>(Y, WO, 1024, X2, nullptr, nullptr, x);

  // ffn path (gate+up fused: WG||WU contiguous = (4096,1024) weight)
  rms_k<<<MROWS, 256, 0, stream>>>(X2, ln2w, H);
  gemm_bt<1024, 3><<<dim3(32, 32), 256, 0, stream>>>(H, WG, 4096, G, U, nullptr, nullptr);
  silumul_k<<<8192, 256, 0, stream>>>(G, U, G, 4096 * 2048);
  gemm_bt<2048, 2><<<dim3(8, 32), 256, 0, stream>>>(G, WD, 1024, (float*)d_out, nullptr, nullptr, X2);
}

// Round 6
// 312.457 us; speedup vs baseline: 1.3455x; 1.3455x over previous
//
#include <hip/hip_runtime.h>
#include <hip/hip_bf16.h>
#include <cstdint>

typedef __hip_bfloat16 bf16;
typedef __attribute__((ext_vector_type(8))) short bf16x8;
typedef __attribute__((ext_vector_type(4))) float f32x4;
typedef __attribute__((ext_vector_type(4))) int i32x4;

#define T_SEQ 2048
#define DMODEL 1024
#define NHEAD 16
#define DHEAD 64
#define MROWS 4096

typedef const __attribute__((address_space(1))) void* gas_ptr;
typedef __attribute__((address_space(3))) void* las_ptr;

static __device__ __forceinline__ f32x4 mfma16(bf16x8 a, bf16x8 b, f32x4 c) {
  return __builtin_amdgcn_mfma_f32_16x16x32_bf16(a, b, c, 0, 0, 0);
}
static __device__ __forceinline__ void gload_lds16(const void* g, void* l) {
  __builtin_amdgcn_global_load_lds((gas_ptr)g, (las_ptr)l, 16, 0, 0);
}
static __device__ __forceinline__ float b2f(unsigned short u) {
  union { unsigned int i; float f; } x; x.i = ((unsigned int)u) << 16; return x.f;
}
static __device__ __forceinline__ unsigned short f2bu(float f) {
  __hip_bfloat16 h = __float2bfloat16(f);
  unsigned short u; __builtin_memcpy(&u, &h, 2); return u;
}

// ---------------- weight fp32 -> bf16 ----------------
__global__ void f2b_k(const float* __restrict__ in, bf16* __restrict__ out, int n) {
  int idx = (blockIdx.x * blockDim.x + threadIdx.x) * 4;
  if (idx < n) {
    float4 v = *(const float4*)(in + idx);
    out[idx]     = __float2bfloat16(v.x);
    out[idx + 1] = __float2bfloat16(v.y);
    out[idx + 2] = __float2bfloat16(v.z);
    out[idx + 3] = __float2bfloat16(v.w);
  }
}

// ---------------- RMSNorm: fp32 in -> bf16 out ----------------
__global__ __launch_bounds__(256) void rms_k(const float* __restrict__ x,
                                             const float* __restrict__ w,
                                             bf16* __restrict__ out) {
  const int row = blockIdx.x;
  const int tid = threadIdx.x;
  const float4 v = ((const float4*)(x + (size_t)row * DMODEL))[tid];
  float ss = v.x * v.x + v.y * v.y + v.z * v.z + v.w * v.w;
#pragma unroll
  for (int off = 32; off; off >>= 1) ss += __shfl_xor(ss, off);
  __shared__ float red[4];
  if ((tid & 63) == 0) red[tid >> 6] = ss;
  __syncthreads();
  const float tot = red[0] + red[1] + red[2] + red[3];
  const float rinv = rsqrtf(tot * (1.f / DMODEL) + 1e-6f);
  const float4 wv = ((const float4*)w)[tid];
  bf16* o = out + (size_t)row * DMODEL + tid * 4;
  o[0] = __float2bfloat16(v.x * rinv * wv.x);
  o[1] = __float2bfloat16(v.y * rinv * wv.y);
  o[2] = __float2bfloat16(v.z * rinv * wv.z);
  o[3] = __float2bfloat16(v.w * rinv * wv.w);
}

// ---------------- GEMM: C = A(M,K) x Bw(N,K)^T, bf16 in, fp32 accum ----------------
// m97 structure: 128x128 tile, BK=32, 4 waves, global_load_lds width=16.
// EPI: 0 = bf16 store to o0 (ld=N)
//      1 = qkv scatter: Q,K as (B,H,T,64) to o0/o1; V TRANSPOSED as (B,H,64,T) to o2
//      2 = fp32 store o0 = res + C (ld=N)
//      3 = split-N: cols [0,N/2) -> o0, [N/2,N) -> o1, each compact ld=N/2 bf16
template <int K, int EPI>
__global__ __launch_bounds__(256) void gemm_bt(const bf16* __restrict__ A,
                                               const bf16* __restrict__ Bw, int N,
                                               void* __restrict__ o0, void* __restrict__ o1,
                                               void* __restrict__ o2,
                                               const float* __restrict__ res) {
  __shared__ bf16 As[128 * 32];
  __shared__ bf16 Bs[128 * 32];
  const int bn0 = blockIdx.x * 128;
  const int bm0 = blockIdx.y * 128;
  const int tid = threadIdx.x;
  const int wave = tid >> 6, lane = tid & 63;
  const int wr = wave >> 1, wc = wave & 1;
  const int fr = lane & 15, g8 = (lane >> 4) * 8, r4 = (lane >> 4) * 4;
  const int srow = lane >> 2;
  const int scol = (lane & 3) * 8;

  const f32x4 fzero = {0.f, 0.f, 0.f, 0.f};
  f32x4 acc[4][4];
#pragma unroll
  for (int i = 0; i < 4; i++)
#pragma unroll
    for (int j = 0; j < 4; j++) acc[i][j] = fzero;

  const bf16* gA0 = A + (size_t)(bm0 + wave * 16 + srow) * K + scol;
  const bf16* gA1 = A + (size_t)(bm0 + (wave + 4) * 16 + srow) * K + scol;
  const bf16* gB0 = Bw + (size_t)(bn0 + wave * 16 + srow) * K + scol;
  const bf16* gB1 = Bw + (size_t)(bn0 + (wave + 4) * 16 + srow) * K + scol;

  for (int k0 = 0; k0 < K; k0 += 32) {
    gload_lds16(gA0 + k0, &As[wave * 512]);
    gload_lds16(gA1 + k0, &As[(wave + 4) * 512]);
    gload_lds16(gB0 + k0, &Bs[wave * 512]);
    gload_lds16(gB1 + k0, &Bs[(wave + 4) * 512]);
    __syncthreads();
    bf16x8 af[4], bfr[4];
#pragma unroll
    for (int mr = 0; mr < 4; mr++)
      af[mr] = *(const bf16x8*)&As[(wr * 64 + mr * 16 + fr) * 32 + g8];
#pragma unroll
    for (int nr = 0; nr < 4; nr++)
      bfr[nr] = *(const bf16x8*)&Bs[(wc * 64 + nr * 16 + fr) * 32 + g8];
#pragma unroll
    for (int mr = 0; mr < 4; mr++)
#pragma unroll
      for (int nr = 0; nr < 4; nr++)
        acc[mr][nr] = mfma16(af[mr], bfr[nr], acc[mr][nr]);
    __syncthreads();
  }

#pragma unroll
  for (int mr = 0; mr < 4; mr++) {
#pragma unroll
    for (int nr = 0; nr < 4; nr++) {
#pragma unroll
      for (int r = 0; r < 4; r++) {
        const int row = bm0 + wr * 64 + mr * 16 + r4 + r;
        const int col = bn0 + wc * 64 + nr * 16 + fr;
        const float vsum = acc[mr][nr][r];
        if (EPI == 0) {
          ((bf16*)o0)[(size_t)row * N + col] = __float2bfloat16(vsum);
        } else if (EPI == 1) {
          const int sel = col >> 10;
          const int n = col & 1023;
          const int h = n >> 6, d = n & 63;
          const int b = row >> 11, t = row & 2047;
          if (sel == 2) {
            // V transposed: (B,H,D,T)
            ((bf16*)o2)[(((size_t)(b * NHEAD + h)) * DHEAD + d) * T_SEQ + t] =
                __float2bfloat16(vsum);
          } else {
            bf16* dst = (sel == 0) ? (bf16*)o0 : (bf16*)o1;
            dst[(((size_t)(b * NHEAD + h)) * T_SEQ + t) * DHEAD + d] = __float2bfloat16(vsum);
          }
        } else if (EPI == 2) {
          ((float*)o0)[(size_t)row * N + col] = res[(size_t)row * N + col] + vsum;
        } else {
          const int half = N >> 1;
          bf16* dst = (col < half) ? (bf16*)o0 : (bf16*)o1;
          const int c = (col < half) ? col : col - half;
          dst[(size_t)row * half + c] = __float2bfloat16(vsum);
        }
      }
    }
  }
}

// ---------------- causal flash attention ----------------
// 2048 balanced wave-tasks: 512 blocks x 4 waves; wave processes Q-group pair
// (p, 127-p) -> every wave ~65 k-iterations (flat occupancy, no drain tail).
// XCD mapping (round-5-verified: FETCH 119MB->12MB): c=blk&7, i=blk>>3,
// bh = c*4 + (i>>4) -> each XCD's L2 serves 4 heads (2MB K+V).
// SWAPPED QK^T: s = mfma(K,Q) = S^T, lane holds q=lane&15, k=(lane>>4)*4+reg.
// P^T for PV's B-operand is rebuilt with 8 __shfl + 4 selects among the 4
// lanes sharing fr — pure register dataflow: NO LDS, NO fences, compiler free
// to pipeline next-iter K/V loads under current PV.
// PV: acc = mfma(V^T, P^T) = O^T (lane holds q=fr, d=nf*16+(lane>>4)*4+r).
// Unnormalized softmax (shift-invariant, exact): p = exp(min(s*0.125,30)).
__global__ __launch_bounds__(256) void attn_k(const bf16* __restrict__ qb,
                                              const bf16* __restrict__ kb,
                                              const bf16* __restrict__ vt,
                                              bf16* __restrict__ y) {
  const int wave = threadIdx.x >> 6, lane = threadIdx.x & 63;
  const int c = blockIdx.x & 7;
  const int i = blockIdx.x >> 3;
  const int bh = c * 4 + (i >> 4);
  const int p = (i & 15) * 4 + wave;
  const int b = bh >> 4, h = bh & 15;
  const int fr = lane & 15, g8 = (lane >> 4) * 8, r4 = (lane >> 4) * 4;
  const int d2 = lane >> 4;                  // P^T dest k-block index
  const int src1 = fr + ((d2 & 1) << 5);     // qg0 / qg2 partner lane
  const int src2 = src1 + 16;                // qg1 / qg3 partner lane
  const bool hB = d2 >= 2;                   // low/high half of k-tile

  const bf16* qp = qb + (size_t)bh * T_SEQ * DHEAD;
  const bf16* kp = kb + (size_t)bh * T_SEQ * DHEAD;
  const bf16* vp = vt + (size_t)bh * DHEAD * T_SEQ;

  const f32x4 fzero = {0.f, 0.f, 0.f, 0.f};

#pragma unroll 1
  for (int ph = 0; ph < 2; ph++) {
    const int g = ph ? (127 - p) : p;
    const int q0 = g * 16;
    const int kend = q0 + 16;
    const int qrow = q0 + fr;

    const bf16x8 qf0 = *(const bf16x8*)(qp + (size_t)(q0 + fr) * DHEAD + g8);
    const bf16x8 qf1 = *(const bf16x8*)(qp + (size_t)(q0 + fr) * DHEAD + 32 + g8);

    f32x4 acc[4];
    float lpart = 0.f;
#pragma unroll
    for (int nf = 0; nf < 4; nf++) acc[nf] = fzero;

    for (int kt = 0; kt < kend; kt += 32) {
      // K rows kt..kt+31 (A operand), V^T rows (B operand source) — independent
      const bf16x8 kf0a = *(const bf16x8*)(kp + (size_t)(kt + fr) * DHEAD + g8);
      const bf16x8 kf0b = *(const bf16x8*)(kp + (size_t)(kt + fr) * DHEAD + 32 + g8);
      const bf16x8 kf1a = *(const bf16x8*)(kp + (size_t)(kt + 16 + fr) * DHEAD + g8);
      const bf16x8 kf1b = *(const bf16x8*)(kp + (size_t)(kt + 16 + fr) * DHEAD + 32 + g8);
      bf16x8 vf[4];
#pragma unroll
      for (int nf = 0; nf < 4; nf++)
        vf[nf] = *(const bf16x8*)(vp + (size_t)(nf * 16 + fr) * T_SEQ + kt + g8);

      // swapped QK^T: S^T[k][q]; lane: q = fr, k_local = r4 + r (+16 for s1)
      f32x4 s0 = mfma16(kf0a, qf0, fzero);
      s0 = mfma16(kf0b, qf1, s0);
      f32x4 s1 = mfma16(kf1a, qf0, fzero);
      s1 = mfma16(kf1b, qf1, s1);

      float x0[4], x1[4];
#pragma unroll
      for (int r = 0; r < 4; r++) {
        const int k0 = kt + r4 + r;
        const int k1 = k0 + 16;
        x0[r] = (k0 <= qrow) ? __expf(fminf(s0[r] * 0.125f, 30.f)) : 0.f;
        x1[r] = (k1 <= qrow) ? __expf(fminf(s1[r] * 0.125f, 30.f)) : 0.f;
        lpart += x0[r] + x1[r];
      }

      // pack P^T values (bf16 pairs along k): lane holds k = {4*d2+r, 16+4*d2+r}
      const int A01 = (int)((unsigned)f2bu(x0[0]) | ((unsigned)f2bu(x0[1]) << 16));
      const int A23 = (int)((unsigned)f2bu(x0[2]) | ((unsigned)f2bu(x0[3]) << 16));
      const int B01 = (int)((unsigned)f2bu(x1[0]) | ((unsigned)f2bu(x1[1]) << 16));
      const int B23 = (int)((unsigned)f2bu(x1[2]) | ((unsigned)f2bu(x1[3]) << 16));

      // rebuild B-frag P^T: dest lane (fr, d2) needs k = 8*d2 .. 8*d2+7
      const int t0a = __shfl(A01, src1), t0b = __shfl(B01, src1);
      const int t1a = __shfl(A23, src1), t1b = __shfl(B23, src1);
      const int t2a = __shfl(A01, src2), t2b = __shfl(B01, src2);
      const int t3a = __shfl(A23, src2), t3b = __shfl(B23, src2);
      i32x4 pw;
      pw[0] = hB ? t0b : t0a;
      pw[1] = hB ? t1b : t1a;
      pw[2] = hB ? t2b : t2a;
      pw[3] = hB ? t3b : t3a;
      const bf16x8 pb = __builtin_bit_cast(bf16x8, pw);

      // PV: O^T = V^T * P^T
#pragma unroll
      for (int nf = 0; nf < 4; nf++) acc[nf] = mfma16(vf[nf], pb, acc[nf]);
    }

    // complete lsum for row q=fr: combine the 4 lanes holding its k-subsets
    lpart += __shfl_xor(lpart, 16);
    lpart += __shfl_xor(lpart, 32);
    const float inv = 1.f / lpart;

    // store O^T: lane (fr, d2): t = q0+fr, d = nf*16 + r4 + 0..3 (8B stores)
    const int t = q0 + fr;
    unsigned short* yb =
        (unsigned short*)(y + (((size_t)(b * T_SEQ + t)) * NHEAD + h) * DHEAD);
#pragma unroll
    for (int nf = 0; nf < 4; nf++) {
      ushort4 ov;
      ov.x = f2bu(acc[nf][0] * inv);
      ov.y = f2bu(acc[nf][1] * inv);
      ov.z = f2bu(acc[nf][2] * inv);
      ov.w = f2bu(acc[nf][3] * inv);
      *(ushort4*)(yb + nf * 16 + r4) = ov;
    }
  }
}

// ---------------- gu = silu(g) * u (bf16) ----------------
__global__ void silumul_k(const bf16* __restrict__ g, const bf16* __restrict__ u,
                          bf16* __restrict__ o, int n) {
  const int idx = (blockIdx.x * blockDim.x + threadIdx.x) * 4;
  if (idx < n) {
    const ushort4 gv = *(const ushort4*)((const unsigned short*)g + idx);
    const ushort4 uv = *(const ushort4*)((const unsigned short*)u + idx);
    ushort4 ov;
    float a, s;
    a = b2f(gv.x); s = a / (1.f + __expf(-a)); ov.x = f2bu(s * b2f(uv.x));
    a = b2f(gv.y); s = a / (1.f + __expf(-a)); ov.y = f2bu(s * b2f(uv.y));
    a = b2f(gv.z); s = a / (1.f + __expf(-a)); ov.z = f2bu(s * b2f(uv.z));
    a = b2f(gv.w); s = a / (1.f + __expf(-a)); ov.w = f2bu(s * b2f(uv.w));
    *(ushort4*)((unsigned short*)o + idx) = ov;
  }
}

// ---------------- launch ----------------
extern "C" void kernel_launch(void* const* d_in, const int* in_sizes, int n_in,
                              void* d_out, int out_size, void* d_ws, size_t ws_size,
                              hipStream_t stream) {
  const float* x     = (const float*)d_in[0];
  const float* ln1w  = (const float*)d_in[1];
  const float* ln2w  = (const float*)d_in[2];
  const float* qkvw  = (const float*)d_in[3];
  const float* ow    = (const float*)d_in[4];
  const float* gatew = (const float*)d_in[5];
  const float* upw   = (const float*)d_in[6];
  const float* downw = (const float*)d_in[7];

  uint8_t* ws = (uint8_t*)d_ws;
  // workspace layout (bytes); ~80 MB total with aliasing
  bf16* WQKV = (bf16*)(ws + 0);          // 6291456
  bf16* WO   = (bf16*)(ws + 6291456);    // 2097152
  bf16* WG   = (bf16*)(ws + 8388608);    // 4194304  (WU must follow contiguously)
  bf16* WU   = (bf16*)(ws + 12582912);   // 4194304
  bf16* WD   = (bf16*)(ws + 16777216);   // 4194304
  bf16* H    = (bf16*)(ws + 20971520);   // 8388608
  bf16* Q    = (bf16*)(ws + 29360128);   // 8388608
  bf16* Kb   = (bf16*)(ws + 37748736);   // 8388608
  bf16* VT   = (bf16*)(ws + 46137344);   // 8388608  (B,H,64,T)
  bf16* Y    = (bf16*)(ws + 54525952);   // 8388608
  float* X2  = (float*)(ws + 62914560);  // 16777216 -> end 79691776
  // FFN phase aliases (Q/Kb/VT/Y dead after o-proj):
  bf16* G = (bf16*)(ws + 29360128);      // 16777216 (4096 x 2048)
  bf16* U = (bf16*)(ws + 46137344);      // 16777216 (4096 x 2048)

  // weights -> bf16
  f2b_k<<<3072, 256, 0, stream>>>(qkvw, WQKV, 3072 * 1024);
  f2b_k<<<1024, 256, 0, stream>>>(ow, WO, 1024 * 1024);
  f2b_k<<<2048, 256, 0, stream>>>(gatew, WG, 2048 * 1024);
  f2b_k<<<2048, 256, 0, stream>>>(upw, WU, 2048 * 1024);
  f2b_k<<<2048, 256, 0, stream>>>(downw, WD, 1024 * 2048);

  // attn path
  rms_k<<<MROWS, 256, 0, stream>>>(x, ln1w, H);
  gemm_bt<1024, 1><<<dim3(24, 32), 256, 0, stream>>>(H, WQKV, 3072, Q, Kb, VT, nullptr);
  attn_k<<<512, 256, 0, stream>>>(Q, Kb, VT, Y);
  gemm_bt<1024, 2><<<dim3(8, 32), 256, 0, stream>>>(Y, WO, 1024, X2, nullptr, nullptr, x);

  // ffn path (gate+up fused: WG||WU contiguous = (4096,1024) weight)
  rms_k<<<MROWS, 256, 0, stream>>>(X2, ln2w, H);
  gemm_bt<1024, 3><<<dim3(32, 32), 256, 0, stream>>>(H, WG, 4096, G, U, nullptr, nullptr);
  silumul_k<<<8192, 256, 0, stream>>>(G, U, G, 4096 * 2048);
  gemm_bt<2048, 2><<<dim3(8, 32), 256, 0, stream>>>(G, WD, 1024, (float*)d_out, nullptr, nullptr, X2);
}